// Round 10
// baseline (41.508 us; speedup 1.0000x reference)
//
#include <hip/hip_runtime.h>

// YOLO-style multi-level detection loss — gridless formulation.
// Input dict order (setup_inputs interleaves!):
//   d_in[0]=cls0 d_in[1]=box0 d_in[2]=obj0
//   d_in[3]=cls1 d_in[4]=box1 d_in[5]=obj1
//   d_in[6]=cls2 d_in[7]=box2 d_in[8]=obj2
//   d_in[9]=boxes [B,N,4]  d_in[10]=labels [B,N]
// Output: 4 floats: total, loss_cls, loss_box, loss_obj
//
// bce(x,t) = bce(x,0) - x*t for t in {0,1}:
//   loss_obj*cnt = sum_all bce0(obj) - sum_poscells obj
//   cls/box terms only need predictions AT positive cells.
// Round-7 lesson: hipMemsetAsync's fillBufferAligned runs ~39us even fully
// cached (tiny latency-bound grid) -> eliminate the grid entirely.
// Collision resolution is intra-batch only (64 boxes = 1 wave): lane n owns
// box n, cells go to LDS, each lane scans 64 entries:
//   winner  <=> no lane m>n maps to my cell   (last box wins = JAX scatter-set)
//   mask     =  OR of labels of lanes sharing my cell (exact)
// Winner lanes gather 20 cls + 4 box + 1 obj preds at their cell.
// No atomics, no workspace clearing (every ws byte written before read each
// call -> poison-proof), 2 dispatches.

#define NCLS  20
#define BATCH 128
#define TPB   256
// cells per level (BATCH * H * W)
#define C0 819200
#define C1 204800
#define C2 51200
// A-blocks: stream bce0(obj) ; one float2 per thread (exact partitions)
#define NA0 1600
#define NA1 400
#define NA2 100
#define NA  (NA0 + NA1 + NA2)   // 2100
// B-blocks: 4 waves each, 1 wave = 1 batch
#define NB  32                  // 32*4 = 128 batches
#define NBLK (NA + NB)          // 2132

struct AllPtrs {
    const float *cls0, *box0, *obj0;
    const float *cls1, *box1, *obj1;
    const float *cls2, *box2, *obj2;
};

__device__ __forceinline__ float bce0(float x) {
    // bce_with_logits(x,0) = max(x,0) + log1p(exp(-|x|)); v_exp/v_log fast
    // form (log(1+e)==log1p(e) to fp32 for e in (2^-24,1]; abs err <=6e-8).
    return fmaxf(x, 0.0f) + __logf(1.0f + __expf(-fabsf(x)));
}

__device__ __forceinline__ float wave_sum(float v) {
    #pragma unroll
    for (int o = 32; o > 0; o >>= 1) v += __shfl_down(v, o);
    return v;
}

__global__ void __launch_bounds__(TPB)
fused_loss(AllPtrs p, const float4* __restrict__ boxes, const int* __restrict__ labels,
           float* __restrict__ Aout, float4* __restrict__ Bout) {
    __shared__ float shA[4];
    __shared__ int   s_cell[4][64];
    __shared__ int   s_lab[4][64];
    __shared__ float shB[4][12];

    int blk = blockIdx.x;
    if (blk < NA) {
        // ---- A path: sum bce0(obj) over all cells of one level slice ----
        const float* obj;
        int i;
        if (blk < NA0)            { obj = p.obj0; i = blk * TPB + threadIdx.x; }
        else if (blk < NA0 + NA1) { obj = p.obj1; i = (blk - NA0) * TPB + threadIdx.x; }
        else                      { obj = p.obj2; i = (blk - NA0 - NA1) * TPB + threadIdx.x; }
        float2 v = ((const float2*)obj)[i];
        float s = bce0(v.x) + bce0(v.y);
        s = wave_sum(s);
        int wid = threadIdx.x >> 6, lane = threadIdx.x & 63;
        if (lane == 0) shA[wid] = s;
        __syncthreads();
        if (threadIdx.x == 0)
            Aout[blk] = shA[0] + shA[1] + shA[2] + shA[3];
        return;
    }

    // ---- B path: per-batch wave-scan winner/mask + positive-cell work ----
    int bb   = blk - NA;            // 0..31
    int wid  = threadIdx.x >> 6;    // wave in block = which batch
    int lane = threadIdx.x & 63;    // box index n
    int batch = bb * 4 + wid;       // 0..127

    float4 bx = boxes[batch * 64 + lane];
    int   lab = labels[batch * 64 + lane];
    float cx = (bx.x + bx.z) * 0.5f, cy = (bx.y + bx.w) * 0.5f;
    float w  = bx.z - bx.x,          h  = bx.w - bx.y;

    const float is[3]   = {0.125f, 0.0625f, 0.03125f};
    const int   Ws[3]   = {80, 40, 20};
    const int   HWs[3]  = {6400, 1600, 400};
    const float* clsP[3] = {p.cls0, p.cls1, p.cls2};
    const float* boxP[3] = {p.box0, p.box1, p.box2};
    const float* objP[3] = {p.obj0, p.obj1, p.obj2};

    float accO[3], accN[3], accC[3], accB[3];

    #pragma unroll
    for (int l = 0; l < 3; ++l) {
        const int Wl = Ws[l], HW = HWs[l];
        int gx = (int)floorf(cx * is[l]);
        int gy = (int)floorf(cy * is[l]);
        bool valid = (gx >= 0) & (gy >= 0) & (gx < Wl) & (gy < Wl);
        int cell = valid ? gy * Wl + gx : -1 - lane;   // unique negatives: no false match
        s_cell[wid][lane] = cell;
        s_lab[wid][lane]  = lab;
        __syncthreads();
        unsigned mask = 0u;
        bool win = valid;
        #pragma unroll 8
        for (int m = 0; m < 64; ++m) {
            int cm = s_cell[wid][m];                   // LDS broadcast read
            if (cm == cell) {
                mask |= 1u << s_lab[wid][m];
                if (m > lane) win = false;             // a later box overwrites
            }
        }
        __syncthreads();                               // before next level reuses LDS
        float aO = 0.f, aN = 0.f, aC = 0.f, aB = 0.f;
        if (win) {
            int rem = cell;                            // level-local spatial idx
            aO = -objP[l][batch * HW + rem];           // bce(x,1)=bce0(x)-x
            aN = 1.f;
            const float* cb = clsP[l] + (batch * NCLS) * HW + rem;
            #pragma unroll
            for (int c = 0; c < NCLS; ++c) {
                float cv = cb[c * HW];
                aC += bce0(cv);
                if ((mask >> c) & 1u) aC -= cv;        // bce(cv,1)=bce0(cv)-cv
            }
            float sx = cx * is[l], sy = cy * is[l];
            float tv0 = sx - floorf(sx);
            float tv1 = sy - floorf(sy);
            float tv2 = __logf(w * is[l] + 1e-6f);
            float tv3 = __logf(h * is[l] + 1e-6f);
            const float* pb = boxP[l] + (batch * 4) * HW + rem;
            float d0 = fabsf(pb[0]      - tv0);
            float d1 = fabsf(pb[HW]     - tv1);
            float d2 = fabsf(pb[2 * HW] - tv2);
            float d3 = fabsf(pb[3 * HW] - tv3);
            aB += (d0 < 1.f) ? 0.5f * d0 * d0 : d0 - 0.5f;
            aB += (d1 < 1.f) ? 0.5f * d1 * d1 : d1 - 0.5f;
            aB += (d2 < 1.f) ? 0.5f * d2 * d2 : d2 - 0.5f;
            aB += (d3 < 1.f) ? 0.5f * d3 * d3 : d3 - 0.5f;
        }
        accO[l] = aO; accN[l] = aN; accC[l] = aC; accB[l] = aB;
    }

    #pragma unroll
    for (int l = 0; l < 3; ++l) {
        float o  = wave_sum(accO[l]);
        float n2 = wave_sum(accN[l]);
        float c2 = wave_sum(accC[l]);
        float b2 = wave_sum(accB[l]);
        if (lane == 0) {
            shB[wid][l * 4 + 0] = o;  shB[wid][l * 4 + 1] = n2;
            shB[wid][l * 4 + 2] = c2; shB[wid][l * 4 + 3] = b2;
        }
    }
    __syncthreads();
    if (threadIdx.x == 0) {
        #pragma unroll
        for (int l = 0; l < 3; ++l) {
            float4 r;
            r.x = shB[0][l*4+0] + shB[1][l*4+0] + shB[2][l*4+0] + shB[3][l*4+0];
            r.y = shB[0][l*4+1] + shB[1][l*4+1] + shB[2][l*4+1] + shB[3][l*4+1];
            r.z = shB[0][l*4+2] + shB[1][l*4+2] + shB[2][l*4+2] + shB[3][l*4+2];
            r.w = shB[0][l*4+3] + shB[1][l*4+3] + shB[2][l*4+3] + shB[3][l*4+3];
            Bout[bb * 3 + l] = r;
        }
    }
}

__global__ void final_combine(const float* __restrict__ Aout, const float4* __restrict__ Bout,
                              float* __restrict__ out) {
    int t = threadIdx.x;
    // A sums per level
    float a0 = 0, a1 = 0, a2 = 0;
    for (int e = t; e < NA0; e += TPB)             a0 += Aout[e];
    for (int e = NA0 + t; e < NA0 + NA1; e += TPB) a1 += Aout[e];
    for (int e = NA0 + NA1 + t; e < NA; e += TPB)  a2 += Aout[e];
    // B sums per level (NB=32 < TPB: one block-row each)
    float o0 = 0, n0 = 0, c0 = 0, b0 = 0;
    float o1 = 0, n1 = 0, c1 = 0, b1 = 0;
    float o2 = 0, n2 = 0, c2 = 0, b2 = 0;
    if (t < NB) {
        float4 v0 = Bout[t * 3 + 0]; o0 = v0.x; n0 = v0.y; c0 = v0.z; b0 = v0.w;
        float4 v1 = Bout[t * 3 + 1]; o1 = v1.x; n1 = v1.y; c1 = v1.z; b1 = v1.w;
        float4 v2 = Bout[t * 3 + 2]; o2 = v2.x; n2 = v2.y; c2 = v2.z; b2 = v2.w;
    }
    a0 = wave_sum(a0); a1 = wave_sum(a1); a2 = wave_sum(a2);
    o0 = wave_sum(o0); n0 = wave_sum(n0); c0 = wave_sum(c0); b0 = wave_sum(b0);
    o1 = wave_sum(o1); n1 = wave_sum(n1); c1 = wave_sum(c1); b1 = wave_sum(b1);
    o2 = wave_sum(o2); n2 = wave_sum(n2); c2 = wave_sum(c2); b2 = wave_sum(b2);
    __shared__ float s[4][15];
    int wid = t >> 6, lane = t & 63;
    if (lane == 0) {
        s[wid][0] = a0; s[wid][1] = a1; s[wid][2] = a2;
        s[wid][3] = o0; s[wid][4]  = n0; s[wid][5]  = c0; s[wid][6]  = b0;
        s[wid][7] = o1; s[wid][8]  = n1; s[wid][9]  = c1; s[wid][10] = b1;
        s[wid][11] = o2; s[wid][12] = n2; s[wid][13] = c2; s[wid][14] = b2;
    }
    __syncthreads();
    if (t == 0) {
        float r[15];
        #pragma unroll
        for (int k = 0; k < 15; ++k)
            r[k] = s[0][k] + s[1][k] + s[2][k] + s[3][k];
        float np0 = fmaxf(r[4],  1.f);
        float np1 = fmaxf(r[8],  1.f);
        float np2 = fmaxf(r[12], 1.f);
        float lo = (r[0] + r[3])  / (float)C0
                 + (r[1] + r[7])  / (float)C1
                 + (r[2] + r[11]) / (float)C2;
        float lc = r[5] / np0 + r[9]  / np1 + r[13] / np2;
        float lb = r[6] / np0 + r[10] / np1 + r[14] / np2;
        out[0] = lc + lb + lo;
        out[1] = lc;
        out[2] = lb;
        out[3] = lo;
    }
}

extern "C" void kernel_launch(void* const* d_in, const int* in_sizes, int n_in,
                              void* d_out, int out_size, void* d_ws, size_t ws_size,
                              hipStream_t stream) {
    AllPtrs p;
    p.cls0 = (const float*)d_in[0]; p.box0 = (const float*)d_in[1]; p.obj0 = (const float*)d_in[2];
    p.cls1 = (const float*)d_in[3]; p.box1 = (const float*)d_in[4]; p.obj1 = (const float*)d_in[5];
    p.cls2 = (const float*)d_in[6]; p.box2 = (const float*)d_in[7]; p.obj2 = (const float*)d_in[8];
    const float4* boxes  = (const float4*)d_in[9];
    const int*    labels = (const int*)d_in[10];
    float* out = (float*)d_out;

    // workspace: Aout[2100] float (8400 B, 16B-aligned end), Bout[96] float4
    char* ws = (char*)d_ws;
    float*  Aout = (float*)ws;
    float4* Bout = (float4*)(ws + NA * sizeof(float));   // offset 8400, %16==0

    fused_loss<<<NBLK, TPB, 0, stream>>>(p, boxes, labels, Aout, Bout);
    final_combine<<<1, TPB, 0, stream>>>(Aout, Bout, out);
}

// Round 11
// 27.517 us; speedup vs baseline: 1.5084x; 1.5084x over previous
//
#include <hip/hip_runtime.h>

// YOLO-style multi-level detection loss — gridless, gather-parallel.
// Input dict order (setup_inputs interleaves!):
//   d_in[0]=cls0 d_in[1]=box0 d_in[2]=obj0
//   d_in[3]=cls1 d_in[4]=box1 d_in[5]=obj1
//   d_in[6]=cls2 d_in[7]=box2 d_in[8]=obj2
//   d_in[9]=boxes [B,N,4]  d_in[10]=labels [B,N]
// Output: 4 floats: total, loss_cls, loss_box, loss_obj
//
// bce(x,t) = bce(x,0) - x*t for t in {0,1}:
//   loss_obj*cnt = sum_all bce0(obj) + sum_winners(-obj)
//   cls/box terms only need predictions AT positive cells.
// Round-10 lesson: 32 B-blocks doing ~25 scattered loads/lane serialized on
// HBM latency (VALUBusy 2.6%, occupancy 4.7%, 50us). Now ONE THREAD PER
// SCATTERED LOAD: 32-lane group per (level,batch,box) entry; lane c<20 = cls
// channel c, 20..23 = box channel, 24 = obj. 3072 G-blocks spread the ~614k
// random-line loads across all 256 CUs (max MLP).
// Winner/mask per entry: batch's 64 cells staged in LDS; lane c probes boxes
// c and c+32; 5-step shfl_xor OR-reduce; bit31 = "a later box shares my cell"
// (last box wins = JAX sequential scatter-set); bits 0..19 = label mask.
// No atomics, no ws clearing (every ws byte written before read each call).

#define NCLS  20
#define BATCH 128
#define TPB   256
// cells per level (BATCH * H * W)
#define C0 819200
#define C1 204800
#define C2 51200
// A-blocks: stream bce0(obj); one float2 per thread (exact partitions)
#define NA0 1600
#define NA1 400
#define NA2 100
#define NA  (NA0 + NA1 + NA2)   // 2100
// G-blocks: 8 entries/block (32 lanes each); 8192 entries/level -> 1024/level
#define NG_PER_LVL 1024
#define NG  (3 * NG_PER_LVL)    // 3072
#define NBLK (NA + NG)          // 5172

struct AllPtrs {
    const float *cls0, *box0, *obj0;
    const float *cls1, *box1, *obj1;
    const float *cls2, *box2, *obj2;
};

__device__ __forceinline__ float bce0(float x) {
    // bce_with_logits(x,0) = max(x,0) + log1p(exp(-|x|)); v_exp/v_log fast
    // form (log(1+e)==log1p(e) to fp32 for e in (2^-24,1]; abs err <=6e-8).
    return fmaxf(x, 0.0f) + __logf(1.0f + __expf(-fabsf(x)));
}

__device__ __forceinline__ float wave_sum(float v) {
    #pragma unroll
    for (int o = 32; o > 0; o >>= 1) v += __shfl_down(v, o);
    return v;
}

__global__ void __launch_bounds__(TPB)
fused_loss(AllPtrs p, const float4* __restrict__ boxes, const int* __restrict__ labels,
           float* __restrict__ Aout, float4* __restrict__ Gout) {
    __shared__ float  shA[4];
    __shared__ int    s_cell[64];
    __shared__ int    s_lab[64];
    __shared__ float  s_cx[64], s_cy[64], s_w[64], s_h[64];
    __shared__ float4 shG[8];

    int blk = blockIdx.x;
    if (blk < NA) {
        // ---- A path: sum bce0(obj) over all cells of one level slice ----
        const float* obj;
        int i;
        if (blk < NA0)            { obj = p.obj0; i = blk * TPB + threadIdx.x; }
        else if (blk < NA0 + NA1) { obj = p.obj1; i = (blk - NA0) * TPB + threadIdx.x; }
        else                      { obj = p.obj2; i = (blk - NA0 - NA1) * TPB + threadIdx.x; }
        float2 v = ((const float2*)obj)[i];
        float s = bce0(v.x) + bce0(v.y);
        s = wave_sum(s);
        int wid = threadIdx.x >> 6, lane = threadIdx.x & 63;
        if (lane == 0) shA[wid] = s;
        __syncthreads();
        if (threadIdx.x == 0)
            Aout[blk] = shA[0] + shA[1] + shA[2] + shA[3];
        return;
    }

    // ---- G path: one 32-lane group per (level,batch,box) entry ----
    int gi = blk - NA;               // 0..3071
    int l  = gi >> 10;               // level 0..2
    int gl = gi & (NG_PER_LVL - 1);  // 0..1023
    int batch  = gl >> 3;            // 0..127 (8 blocks per batch)
    int base_n = (gl & 7) * 8;       // this block's 8 box indices

    const float is[3]  = {0.125f, 0.0625f, 0.03125f};
    const int   Ws[3]  = {80, 40, 20};
    const int   HWs[3] = {6400, 1600, 400};
    const float* clsP[3] = {p.cls0, p.cls1, p.cls2};
    const float* boxP[3] = {p.box0, p.box1, p.box2};
    const float* objP[3] = {p.obj0, p.obj1, p.obj2};
    const float isl = is[l];
    const int   Wl  = Ws[l];
    const int   HW  = HWs[l];

    int t = threadIdx.x;
    if (t < 64) {                    // stage batch geometry in LDS
        float4 bx = boxes[batch * 64 + t];
        float cx = (bx.x + bx.z) * 0.5f, cy = (bx.y + bx.w) * 0.5f;
        s_cx[t] = cx; s_cy[t] = cy;
        s_w[t]  = bx.z - bx.x; s_h[t] = bx.w - bx.y;
        s_lab[t] = labels[batch * 64 + t];
        int gx = (int)floorf(cx * isl);
        int gy = (int)floorf(cy * isl);
        bool valid = (gx >= 0) & (gy >= 0) & (gx < Wl) & (gy < Wl);
        s_cell[t] = valid ? gy * Wl + gx : -1;
    }
    __syncthreads();

    int g = t >> 5;                  // entry group 0..7
    int c = t & 31;                  // channel lane
    int n = base_n + g;              // this group's box index
    int cell = s_cell[n];

    // winner + label-mask scan: lane c probes boxes c and c+32
    unsigned comb = 0u;              // bits0..19 label mask, bit31 violation
    if (cell >= 0) {
        if (s_cell[c] == cell)
            comb |= (1u << s_lab[c]) | ((c > n) ? 0x80000000u : 0u);
        if (s_cell[c + 32] == cell)
            comb |= (1u << s_lab[c + 32]) | 0x80000000u;   // c+32 > n always (n<=63, but only matters if match & >n; c+32>=32>base_n+7 only if... n can be up to 63)
    }
    // NOTE: c+32 ranges 32..63; n ranges base_n..base_n+7 which can reach 63.
    // So the ">n" test for j=c+32 is NOT always true; redo precisely:
    if (cell >= 0 && s_cell[c + 32] == cell && (c + 32) <= n)
        comb &= ~0x80000000u ^ 0u;   // placeholder, fixed below
    // (recompute cleanly to avoid the shortcut above)
    comb = 0u;
    if (cell >= 0) {
        int j0 = c, j1 = c + 32;
        if (s_cell[j0] == cell) comb |= (1u << s_lab[j0]) | ((j0 > n) ? 0x80000000u : 0u);
        if (s_cell[j1] == cell) comb |= (1u << s_lab[j1]) | ((j1 > n) ? 0x80000000u : 0u);
    }
    #pragma unroll
    for (int o = 16; o > 0; o >>= 1)
        comb |= (unsigned)__shfl_xor((int)comb, o, 32);
    bool win = (cell >= 0) && !(comb >> 31);
    unsigned mask = comb & 0xFFFFFu;

    // one scattered load per thread
    float v_cls = 0.f, v_box = 0.f, v_obj = 0.f;
    if (win) {
        if (c < NCLS) {
            float cv = clsP[l][(batch * NCLS + c) * HW + cell];
            v_cls = bce0(cv) - (((mask >> c) & 1u) ? cv : 0.f);
        } else if (c < 24) {
            int k = c - 20;
            float tv;
            if (k == 0)      { float sx = s_cx[n] * isl; tv = sx - floorf(sx); }
            else if (k == 1) { float sy = s_cy[n] * isl; tv = sy - floorf(sy); }
            else if (k == 2) { tv = __logf(s_w[n] * isl + 1e-6f); }
            else             { tv = __logf(s_h[n] * isl + 1e-6f); }
            float pb = boxP[l][(batch * 4 + k) * HW + cell];
            float d = fabsf(pb - tv);
            v_box = (d < 1.f) ? 0.5f * d * d : d - 0.5f;
        } else if (c == 24) {
            v_obj = -objP[l][batch * HW + cell];   // bce(x,1)=bce0(x)-x
        }
    }
    #pragma unroll
    for (int o = 16; o > 0; o >>= 1) {
        v_cls += __shfl_down(v_cls, o, 32);
        v_box += __shfl_down(v_box, o, 32);
    }
    float s_obj = __shfl(v_obj, 24, 32);
    if (c == 0)
        shG[g] = make_float4(s_obj, win ? 1.f : 0.f, v_cls, v_box);
    __syncthreads();
    if (t == 0) {
        float4 r = make_float4(0.f, 0.f, 0.f, 0.f);
        #pragma unroll
        for (int k = 0; k < 8; ++k) {
            r.x += shG[k].x; r.y += shG[k].y; r.z += shG[k].z; r.w += shG[k].w;
        }
        Gout[gi] = r;
    }
}

__global__ void final_combine(const float* __restrict__ Aout, const float4* __restrict__ Gout,
                              float* __restrict__ out) {
    int t = threadIdx.x;
    // A sums per level
    float a0 = 0, a1 = 0, a2 = 0;
    for (int e = t; e < NA0; e += TPB)             a0 += Aout[e];
    for (int e = NA0 + t; e < NA0 + NA1; e += TPB) a1 += Aout[e];
    for (int e = NA0 + NA1 + t; e < NA; e += TPB)  a2 += Aout[e];
    // G sums per level (1024 float4 each)
    float o0 = 0, n0 = 0, c0 = 0, b0 = 0;
    float o1 = 0, n1 = 0, c1 = 0, b1 = 0;
    float o2 = 0, n2 = 0, c2 = 0, b2 = 0;
    for (int e = t; e < NG_PER_LVL; e += TPB) {
        float4 v = Gout[e];                  o0 += v.x; n0 += v.y; c0 += v.z; b0 += v.w;
    }
    for (int e = t; e < NG_PER_LVL; e += TPB) {
        float4 v = Gout[NG_PER_LVL + e];     o1 += v.x; n1 += v.y; c1 += v.z; b1 += v.w;
    }
    for (int e = t; e < NG_PER_LVL; e += TPB) {
        float4 v = Gout[2 * NG_PER_LVL + e]; o2 += v.x; n2 += v.y; c2 += v.z; b2 += v.w;
    }
    a0 = wave_sum(a0); a1 = wave_sum(a1); a2 = wave_sum(a2);
    o0 = wave_sum(o0); n0 = wave_sum(n0); c0 = wave_sum(c0); b0 = wave_sum(b0);
    o1 = wave_sum(o1); n1 = wave_sum(n1); c1 = wave_sum(c1); b1 = wave_sum(b1);
    o2 = wave_sum(o2); n2 = wave_sum(n2); c2 = wave_sum(c2); b2 = wave_sum(b2);
    __shared__ float s[4][15];
    int wid = t >> 6, lane = t & 63;
    if (lane == 0) {
        s[wid][0] = a0; s[wid][1] = a1; s[wid][2] = a2;
        s[wid][3]  = o0; s[wid][4]  = n0; s[wid][5]  = c0; s[wid][6]  = b0;
        s[wid][7]  = o1; s[wid][8]  = n1; s[wid][9]  = c1; s[wid][10] = b1;
        s[wid][11] = o2; s[wid][12] = n2; s[wid][13] = c2; s[wid][14] = b2;
    }
    __syncthreads();
    if (t == 0) {
        float r[15];
        #pragma unroll
        for (int k = 0; k < 15; ++k)
            r[k] = s[0][k] + s[1][k] + s[2][k] + s[3][k];
        float np0 = fmaxf(r[4],  1.f);
        float np1 = fmaxf(r[8],  1.f);
        float np2 = fmaxf(r[12], 1.f);
        float lo = (r[0] + r[3])  / (float)C0
                 + (r[1] + r[7])  / (float)C1
                 + (r[2] + r[11]) / (float)C2;
        float lc = r[5] / np0 + r[9]  / np1 + r[13] / np2;
        float lb = r[6] / np0 + r[10] / np1 + r[14] / np2;
        out[0] = lc + lb + lo;
        out[1] = lc;
        out[2] = lb;
        out[3] = lo;
    }
}

extern "C" void kernel_launch(void* const* d_in, const int* in_sizes, int n_in,
                              void* d_out, int out_size, void* d_ws, size_t ws_size,
                              hipStream_t stream) {
    AllPtrs p;
    p.cls0 = (const float*)d_in[0]; p.box0 = (const float*)d_in[1]; p.obj0 = (const float*)d_in[2];
    p.cls1 = (const float*)d_in[3]; p.box1 = (const float*)d_in[4]; p.obj1 = (const float*)d_in[5];
    p.cls2 = (const float*)d_in[6]; p.box2 = (const float*)d_in[7]; p.obj2 = (const float*)d_in[8];
    const float4* boxes  = (const float4*)d_in[9];
    const int*    labels = (const int*)d_in[10];
    float* out = (float*)d_out;

    // workspace: Gout float4[3072] at 0 (49152 B), Aout float[2100] after
    char* ws = (char*)d_ws;
    float4* Gout = (float4*)ws;
    float*  Aout = (float*)(ws + NG * sizeof(float4));

    fused_loss<<<NBLK, TPB, 0, stream>>>(p, boxes, labels, Aout, Gout);
    final_combine<<<1, TPB, 0, stream>>>(Aout, Gout, out);
}

// Round 12
// 25.063 us; speedup vs baseline: 1.6561x; 1.0979x over previous
//
#include <hip/hip_runtime.h>

// YOLO-style multi-level detection loss — gridless, gather-parallel.
// Input dict order (setup_inputs interleaves!):
//   d_in[0]=cls0 d_in[1]=box0 d_in[2]=obj0
//   d_in[3]=cls1 d_in[4]=box1 d_in[5]=obj1
//   d_in[6]=cls2 d_in[7]=box2 d_in[8]=obj2
//   d_in[9]=boxes [B,N,4]  d_in[10]=labels [B,N]
// Output: 4 floats: total, loss_cls, loss_box, loss_obj
//
// bce(x,t) = bce(x,0) - x*t for t in {0,1}:
//   loss_obj*cnt = sum_all bce0(obj) + sum_winners(-obj)
//   cls/box terms only need predictions AT positive cells.
// Round-11 lesson: G-block critical path was serial {stage-latency -> scan ->
// gather-latency}; ~1.1 TB/s effective random BW. Now ISSUE-EARLY: scattered
// load issued right after cell is known (safe fallback addr), LDS scan + tv
// VALU overlap the load latency; win/mask applied post-scan. G-blocks
// dispatched FIRST (latency-critical), streaming A-blocks fill bubbles.
// One thread per scattered load: 32-lane group per (level,batch,box) entry;
// lane c<20 = cls channel c, 20..23 = box channel, 24 = obj.
// Winner/mask: batch's 64 cells in LDS; lane c probes boxes c and c+32;
// 5-step shfl_xor OR-reduce; bit31 = "later box shares my cell" (last box
// wins = JAX sequential scatter-set); bits 0..19 = label mask.
// No atomics, no ws clearing (every ws byte written before read each call).

#define NCLS  20
#define BATCH 128
#define TPB   256
// cells per level (BATCH * H * W)
#define C0 819200
#define C1 204800
#define C2 51200
// G-blocks: 8 entries/block (32 lanes each); 8192 entries/level -> 1024/level
#define NG_PER_LVL 1024
#define NG  (3 * NG_PER_LVL)    // 3072
// A-blocks: stream bce0(obj); one float2 per thread (exact partitions)
#define NA0 1600
#define NA1 400
#define NA2 100
#define NA  (NA0 + NA1 + NA2)   // 2100
#define NBLK (NG + NA)          // 5172

struct AllPtrs {
    const float *cls0, *box0, *obj0;
    const float *cls1, *box1, *obj1;
    const float *cls2, *box2, *obj2;
};

__device__ __forceinline__ float bce0(float x) {
    // bce_with_logits(x,0) = max(x,0) + log1p(exp(-|x|)); v_exp/v_log fast
    // form (log(1+e)==log1p(e) to fp32 for e in (2^-24,1]; abs err <=6e-8).
    return fmaxf(x, 0.0f) + __logf(1.0f + __expf(-fabsf(x)));
}

__device__ __forceinline__ float wave_sum(float v) {
    #pragma unroll
    for (int o = 32; o > 0; o >>= 1) v += __shfl_down(v, o);
    return v;
}

__global__ void __launch_bounds__(TPB)
fused_loss(AllPtrs p, const float4* __restrict__ boxes, const int* __restrict__ labels,
           float* __restrict__ Aout, float4* __restrict__ Gout) {
    __shared__ float  shA[4];
    __shared__ int    s_cell[64];
    __shared__ int    s_lab[64];
    __shared__ float  s_cx[64], s_cy[64], s_w[64], s_h[64];
    __shared__ float4 shG[8];

    int blk = blockIdx.x;
    if (blk >= NG) {
        // ---- A path: sum bce0(obj) over all cells of one level slice ----
        int a = blk - NG;
        const float* obj;
        int i;
        if (a < NA0)            { obj = p.obj0; i = a * TPB + threadIdx.x; }
        else if (a < NA0 + NA1) { obj = p.obj1; i = (a - NA0) * TPB + threadIdx.x; }
        else                    { obj = p.obj2; i = (a - NA0 - NA1) * TPB + threadIdx.x; }
        float2 v = ((const float2*)obj)[i];
        float s = bce0(v.x) + bce0(v.y);
        s = wave_sum(s);
        int wid = threadIdx.x >> 6, lane = threadIdx.x & 63;
        if (lane == 0) shA[wid] = s;
        __syncthreads();
        if (threadIdx.x == 0)
            Aout[a] = shA[0] + shA[1] + shA[2] + shA[3];
        return;
    }

    // ---- G path: one 32-lane group per (level,batch,box) entry ----
    int gi = blk;                    // 0..3071
    int l  = gi >> 10;               // level 0..2
    int gl = gi & (NG_PER_LVL - 1);  // 0..1023
    int batch  = gl >> 3;            // 0..127 (8 blocks per batch)
    int base_n = (gl & 7) * 8;       // this block's 8 box indices

    const float is[3]  = {0.125f, 0.0625f, 0.03125f};
    const int   Ws[3]  = {80, 40, 20};
    const int   HWs[3] = {6400, 1600, 400};
    const float* clsP[3] = {p.cls0, p.cls1, p.cls2};
    const float* boxP[3] = {p.box0, p.box1, p.box2};
    const float* objP[3] = {p.obj0, p.obj1, p.obj2};
    const float isl = is[l];
    const int   Wl  = Ws[l];
    const int   HW  = HWs[l];

    int t = threadIdx.x;
    if (t < 64) {                    // stage batch geometry in LDS
        float4 bx = boxes[batch * 64 + t];
        float cx = (bx.x + bx.z) * 0.5f, cy = (bx.y + bx.w) * 0.5f;
        s_cx[t] = cx; s_cy[t] = cy;
        s_w[t]  = bx.z - bx.x; s_h[t] = bx.w - bx.y;
        s_lab[t] = labels[batch * 64 + t];
        int gx = (int)floorf(cx * isl);
        int gy = (int)floorf(cy * isl);
        bool valid = (gx >= 0) & (gy >= 0) & (gx < Wl) & (gy < Wl);
        s_cell[t] = valid ? gy * Wl + gx : -1;
    }
    __syncthreads();

    int g = t >> 5;                  // entry group 0..7
    int c = t & 31;                  // channel lane
    int n = base_n + g;              // this group's box index
    int cell  = s_cell[n];
    int lcell = (cell >= 0) ? cell : 0;   // safe fallback address

    // ---- ISSUE scattered load EARLY (latency overlaps scan + tv calc) ----
    float ld = 0.f;
    if (c < NCLS)       ld = clsP[l][(batch * NCLS + c) * HW + lcell];
    else if (c < 24)    ld = boxP[l][(batch * 4 + (c - 20)) * HW + lcell];
    else if (c == 24)   ld = objP[l][batch * HW + lcell];

    // box-target value for lanes 20..23 (independent of load)
    float tv = 0.f;
    if (c >= 20 && c < 24) {
        int k = c - 20;
        if (k == 0)      { float sx = s_cx[n] * isl; tv = sx - floorf(sx); }
        else if (k == 1) { float sy = s_cy[n] * isl; tv = sy - floorf(sy); }
        else if (k == 2) { tv = __logf(s_w[n] * isl + 1e-6f); }
        else             { tv = __logf(s_h[n] * isl + 1e-6f); }
    }

    // ---- winner + label-mask scan (overlaps load latency) ----
    unsigned comb = 0u;              // bits0..19 label mask, bit31 violation
    if (cell >= 0) {
        if (s_cell[c] == cell)
            comb |= (1u << s_lab[c]) | ((c > n) ? 0x80000000u : 0u);
        if (s_cell[c + 32] == cell)
            comb |= (1u << s_lab[c + 32]) | ((c + 32 > n) ? 0x80000000u : 0u);
    }
    #pragma unroll
    for (int o = 16; o > 0; o >>= 1)
        comb |= (unsigned)__shfl_xor((int)comb, o, 32);
    bool win = (cell >= 0) && !(comb >> 31);
    unsigned mask = comb & 0xFFFFFu;

    // ---- apply win/mask to loaded value ----
    float v_cls = 0.f, v_box = 0.f, v_obj = 0.f;
    if (win) {
        if (c < NCLS) {
            v_cls = bce0(ld) - (((mask >> c) & 1u) ? ld : 0.f);
        } else if (c < 24) {
            float d = fabsf(ld - tv);
            v_box = (d < 1.f) ? 0.5f * d * d : d - 0.5f;
        } else if (c == 24) {
            v_obj = -ld;                       // bce(x,1)=bce0(x)-x
        }
    }
    #pragma unroll
    for (int o = 16; o > 0; o >>= 1) {
        v_cls += __shfl_down(v_cls, o, 32);
        v_box += __shfl_down(v_box, o, 32);
    }
    float s_obj = __shfl(v_obj, 24, 32);
    if (c == 0)
        shG[g] = make_float4(s_obj, win ? 1.f : 0.f, v_cls, v_box);
    __syncthreads();
    if (t == 0) {
        float4 r = make_float4(0.f, 0.f, 0.f, 0.f);
        #pragma unroll
        for (int k = 0; k < 8; ++k) {
            r.x += shG[k].x; r.y += shG[k].y; r.z += shG[k].z; r.w += shG[k].w;
        }
        Gout[gi] = r;
    }
}

__global__ void final_combine(const float* __restrict__ Aout, const float4* __restrict__ Gout,
                              float* __restrict__ out) {
    int t = threadIdx.x;
    // A sums per level
    float a0 = 0, a1 = 0, a2 = 0;
    for (int e = t; e < NA0; e += TPB)             a0 += Aout[e];
    for (int e = NA0 + t; e < NA0 + NA1; e += TPB) a1 += Aout[e];
    for (int e = NA0 + NA1 + t; e < NA; e += TPB)  a2 += Aout[e];
    // G sums per level (1024 float4 each)
    float o0 = 0, n0 = 0, c0 = 0, b0 = 0;
    float o1 = 0, n1 = 0, c1 = 0, b1 = 0;
    float o2 = 0, n2 = 0, c2 = 0, b2 = 0;
    for (int e = t; e < NG_PER_LVL; e += TPB) {
        float4 v = Gout[e];                  o0 += v.x; n0 += v.y; c0 += v.z; b0 += v.w;
    }
    for (int e = t; e < NG_PER_LVL; e += TPB) {
        float4 v = Gout[NG_PER_LVL + e];     o1 += v.x; n1 += v.y; c1 += v.z; b1 += v.w;
    }
    for (int e = t; e < NG_PER_LVL; e += TPB) {
        float4 v = Gout[2 * NG_PER_LVL + e]; o2 += v.x; n2 += v.y; c2 += v.z; b2 += v.w;
    }
    a0 = wave_sum(a0); a1 = wave_sum(a1); a2 = wave_sum(a2);
    o0 = wave_sum(o0); n0 = wave_sum(n0); c0 = wave_sum(c0); b0 = wave_sum(b0);
    o1 = wave_sum(o1); n1 = wave_sum(n1); c1 = wave_sum(c1); b1 = wave_sum(b1);
    o2 = wave_sum(o2); n2 = wave_sum(n2); c2 = wave_sum(c2); b2 = wave_sum(b2);
    __shared__ float s[4][15];
    int wid = t >> 6, lane = t & 63;
    if (lane == 0) {
        s[wid][0] = a0; s[wid][1] = a1; s[wid][2] = a2;
        s[wid][3]  = o0; s[wid][4]  = n0; s[wid][5]  = c0; s[wid][6]  = b0;
        s[wid][7]  = o1; s[wid][8]  = n1; s[wid][9]  = c1; s[wid][10] = b1;
        s[wid][11] = o2; s[wid][12] = n2; s[wid][13] = c2; s[wid][14] = b2;
    }
    __syncthreads();
    if (t == 0) {
        float r[15];
        #pragma unroll
        for (int k = 0; k < 15; ++k)
            r[k] = s[0][k] + s[1][k] + s[2][k] + s[3][k];
        float np0 = fmaxf(r[4],  1.f);
        float np1 = fmaxf(r[8],  1.f);
        float np2 = fmaxf(r[12], 1.f);
        float lo = (r[0] + r[3])  / (float)C0
                 + (r[1] + r[7])  / (float)C1
                 + (r[2] + r[11]) / (float)C2;
        float lc = r[5] / np0 + r[9]  / np1 + r[13] / np2;
        float lb = r[6] / np0 + r[10] / np1 + r[14] / np2;
        out[0] = lc + lb + lo;
        out[1] = lc;
        out[2] = lb;
        out[3] = lo;
    }
}

extern "C" void kernel_launch(void* const* d_in, const int* in_sizes, int n_in,
                              void* d_out, int out_size, void* d_ws, size_t ws_size,
                              hipStream_t stream) {
    AllPtrs p;
    p.cls0 = (const float*)d_in[0]; p.box0 = (const float*)d_in[1]; p.obj0 = (const float*)d_in[2];
    p.cls1 = (const float*)d_in[3]; p.box1 = (const float*)d_in[4]; p.obj1 = (const float*)d_in[5];
    p.cls2 = (const float*)d_in[6]; p.box2 = (const float*)d_in[7]; p.obj2 = (const float*)d_in[8];
    const float4* boxes  = (const float4*)d_in[9];
    const int*    labels = (const int*)d_in[10];
    float* out = (float*)d_out;

    // workspace: Gout float4[3072] at 0 (49152 B), Aout float[2100] after
    char* ws = (char*)d_ws;
    float4* Gout = (float4*)ws;
    float*  Aout = (float*)(ws + NG * sizeof(float4));

    fused_loss<<<NBLK, TPB, 0, stream>>>(p, boxes, labels, Aout, Gout);
    final_combine<<<1, TPB, 0, stream>>>(Aout, Gout, out);
}

// Round 13
// 23.498 us; speedup vs baseline: 1.7664x; 1.0666x over previous
//
#include <hip/hip_runtime.h>

// YOLO-style multi-level detection loss — gridless, gather-parallel, 2-deep MLP.
// Input dict order (setup_inputs interleaves!):
//   d_in[0]=cls0 d_in[1]=box0 d_in[2]=obj0
//   d_in[3]=cls1 d_in[4]=box1 d_in[5]=obj1
//   d_in[6]=cls2 d_in[7]=box2 d_in[8]=obj2
//   d_in[9]=boxes [B,N,4]  d_in[10]=labels [B,N]
// Output: 4 floats: total, loss_cls, loss_box, loss_obj
//
// bce(x,t) = bce(x,0) - x*t for t in {0,1}:
//   loss_obj*cnt = sum_all bce0(obj) + sum_winners(-obj)
//   cls/box terms only need predictions AT positive cells.
// Round-12 state: gather phase ~17us, FETCH 22.5MB (structural line overfetch),
// ~1.3 TB/s effective scattered throughput. Test: issue TWO scattered loads per
// thread (2 entries per 32-lane group) -> 2x loads in flight, half the blocks
// (shorter tail), half the partials. If neutral -> MSHR/latency roofline.
// One thread per scattered load: lane c<20 = cls channel c, 20..23 = box
// channel, 24 = obj. Winner/mask: batch's 64 cells in LDS; lane c probes
// boxes c and c+32 for both entries; shared 5-step shfl_xor OR-reduce;
// bit31 = "later box shares my cell" (last box wins = JAX scatter-set);
// bits 0..19 = label mask. No atomics, no ws clearing (poison-proof).

#define NCLS  20
#define BATCH 128
#define TPB   256
// cells per level (BATCH * H * W)
#define C0 819200
#define C1 204800
#define C2 51200
// G-blocks: 16 entries/block (8 groups x 2); 8192 entries/level -> 512/level
#define NG_PER_LVL 512
#define NG  (3 * NG_PER_LVL)    // 1536
// A-blocks: stream bce0(obj); one float2 per thread (exact partitions)
#define NA0 1600
#define NA1 400
#define NA2 100
#define NA  (NA0 + NA1 + NA2)   // 2100
#define NBLK (NG + NA)          // 3636

struct AllPtrs {
    const float *cls0, *box0, *obj0;
    const float *cls1, *box1, *obj1;
    const float *cls2, *box2, *obj2;
};

__device__ __forceinline__ float bce0(float x) {
    // bce_with_logits(x,0) = max(x,0) + log1p(exp(-|x|)); v_exp/v_log fast
    // form (log(1+e)==log1p(e) to fp32 for e in (2^-24,1]; abs err <=6e-8).
    return fmaxf(x, 0.0f) + __logf(1.0f + __expf(-fabsf(x)));
}

__device__ __forceinline__ float wave_sum(float v) {
    #pragma unroll
    for (int o = 32; o > 0; o >>= 1) v += __shfl_down(v, o);
    return v;
}

__global__ void __launch_bounds__(TPB)
fused_loss(AllPtrs p, const float4* __restrict__ boxes, const int* __restrict__ labels,
           float* __restrict__ Aout, float4* __restrict__ Gout) {
    __shared__ float  shA[4];
    __shared__ int    s_cell[64];
    __shared__ int    s_lab[64];
    __shared__ float  s_cx[64], s_cy[64], s_w[64], s_h[64];
    __shared__ float4 shG[8];

    int blk = blockIdx.x;
    if (blk >= NG) {
        // ---- A path: sum bce0(obj) over all cells of one level slice ----
        int a = blk - NG;
        const float* obj;
        int i;
        if (a < NA0)            { obj = p.obj0; i = a * TPB + threadIdx.x; }
        else if (a < NA0 + NA1) { obj = p.obj1; i = (a - NA0) * TPB + threadIdx.x; }
        else                    { obj = p.obj2; i = (a - NA0 - NA1) * TPB + threadIdx.x; }
        float2 v = ((const float2*)obj)[i];
        float s = bce0(v.x) + bce0(v.y);
        s = wave_sum(s);
        int wid = threadIdx.x >> 6, lane = threadIdx.x & 63;
        if (lane == 0) shA[wid] = s;
        __syncthreads();
        if (threadIdx.x == 0)
            Aout[a] = shA[0] + shA[1] + shA[2] + shA[3];
        return;
    }

    // ---- G path: one 32-lane group per TWO (level,batch,box) entries ----
    int gi  = blk;                    // 0..1535
    int l   = gi >> 9;                // level 0..2
    int rem = gi & (NG_PER_LVL - 1);  // 0..511
    int batch  = rem >> 2;            // 0..127 (4 blocks per batch)
    int base_n = (rem & 3) * 16;      // this block's 16 box indices

    const float is[3]  = {0.125f, 0.0625f, 0.03125f};
    const int   Ws[3]  = {80, 40, 20};
    const int   HWs[3] = {6400, 1600, 400};
    const float* clsP[3] = {p.cls0, p.cls1, p.cls2};
    const float* boxP[3] = {p.box0, p.box1, p.box2};
    const float* objP[3] = {p.obj0, p.obj1, p.obj2};
    const float isl = is[l];
    const int   Wl  = Ws[l];
    const int   HW  = HWs[l];

    int t = threadIdx.x;
    if (t < 64) {                    // stage batch geometry in LDS
        float4 bx = boxes[batch * 64 + t];
        float cx = (bx.x + bx.z) * 0.5f, cy = (bx.y + bx.w) * 0.5f;
        s_cx[t] = cx; s_cy[t] = cy;
        s_w[t]  = bx.z - bx.x; s_h[t] = bx.w - bx.y;
        s_lab[t] = labels[batch * 64 + t];
        int gx = (int)floorf(cx * isl);
        int gy = (int)floorf(cy * isl);
        bool valid = (gx >= 0) & (gy >= 0) & (gx < Wl) & (gy < Wl);
        s_cell[t] = valid ? gy * Wl + gx : -1;
    }
    __syncthreads();

    int g  = t >> 5;                 // group 0..7
    int c  = t & 31;                 // channel lane
    int n0 = base_n + g;             // entry 0 box index
    int n1 = base_n + g + 8;         // entry 1 box index
    int cell0 = s_cell[n0], cell1 = s_cell[n1];
    int lc0 = (cell0 >= 0) ? cell0 : 0;
    int lc1 = (cell1 >= 0) ? cell1 : 0;

    // ---- ISSUE both scattered loads EARLY (latency overlaps scan) ----
    float ld0 = 0.f, ld1 = 0.f;
    if (c < NCLS) {
        const float* cb = clsP[l] + (size_t)(batch * NCLS + c) * HW;
        ld0 = cb[lc0]; ld1 = cb[lc1];
    } else if (c < 24) {
        const float* bb = boxP[l] + (size_t)(batch * 4 + (c - 20)) * HW;
        ld0 = bb[lc0]; ld1 = bb[lc1];
    } else if (c == 24) {
        const float* ob = objP[l] + (size_t)batch * HW;
        ld0 = ob[lc0]; ld1 = ob[lc1];
    }

    // box-target values for lanes 20..23 (independent of loads)
    float tv0 = 0.f, tv1 = 0.f;
    if (c >= 20 && c < 24) {
        int k = c - 20;
        if (k == 0) {
            float sx0 = s_cx[n0] * isl; tv0 = sx0 - floorf(sx0);
            float sx1 = s_cx[n1] * isl; tv1 = sx1 - floorf(sx1);
        } else if (k == 1) {
            float sy0 = s_cy[n0] * isl; tv0 = sy0 - floorf(sy0);
            float sy1 = s_cy[n1] * isl; tv1 = sy1 - floorf(sy1);
        } else if (k == 2) {
            tv0 = __logf(s_w[n0] * isl + 1e-6f);
            tv1 = __logf(s_w[n1] * isl + 1e-6f);
        } else {
            tv0 = __logf(s_h[n0] * isl + 1e-6f);
            tv1 = __logf(s_h[n1] * isl + 1e-6f);
        }
    }

    // ---- winner + label-mask scan for both entries (overlaps loads) ----
    int cj0 = s_cell[c], cj1 = s_cell[c + 32];
    int lj0 = s_lab[c],  lj1 = s_lab[c + 32];
    unsigned comb0 = 0u, comb1 = 0u;   // bits0..19 mask, bit31 violation
    if (cell0 >= 0) {
        if (cj0 == cell0) comb0 |= (1u << lj0) | ((c > n0)      ? 0x80000000u : 0u);
        if (cj1 == cell0) comb0 |= (1u << lj1) | ((c + 32 > n0) ? 0x80000000u : 0u);
    }
    if (cell1 >= 0) {
        if (cj0 == cell1) comb1 |= (1u << lj0) | ((c > n1)      ? 0x80000000u : 0u);
        if (cj1 == cell1) comb1 |= (1u << lj1) | ((c + 32 > n1) ? 0x80000000u : 0u);
    }
    #pragma unroll
    for (int o = 16; o > 0; o >>= 1) {
        comb0 |= (unsigned)__shfl_xor((int)comb0, o, 32);
        comb1 |= (unsigned)__shfl_xor((int)comb1, o, 32);
    }
    bool win0 = (cell0 >= 0) && !(comb0 >> 31);
    bool win1 = (cell1 >= 0) && !(comb1 >> 31);
    unsigned mask0 = comb0 & 0xFFFFFu;
    unsigned mask1 = comb1 & 0xFFFFFu;

    // ---- apply win/mask to loaded values ----
    float v_cls = 0.f, v_box = 0.f, v_obj = 0.f;
    if (c < NCLS) {
        if (win0) v_cls += bce0(ld0) - (((mask0 >> c) & 1u) ? ld0 : 0.f);
        if (win1) v_cls += bce0(ld1) - (((mask1 >> c) & 1u) ? ld1 : 0.f);
    } else if (c < 24) {
        if (win0) { float d = fabsf(ld0 - tv0); v_box += (d < 1.f) ? 0.5f * d * d : d - 0.5f; }
        if (win1) { float d = fabsf(ld1 - tv1); v_box += (d < 1.f) ? 0.5f * d * d : d - 0.5f; }
    } else if (c == 24) {
        if (win0) v_obj -= ld0;            // bce(x,1)=bce0(x)-x
        if (win1) v_obj -= ld1;
    }
    #pragma unroll
    for (int o = 16; o > 0; o >>= 1) {
        v_cls += __shfl_down(v_cls, o, 32);
        v_box += __shfl_down(v_box, o, 32);
    }
    float s_obj = __shfl(v_obj, 24, 32);
    float s_np  = (win0 ? 1.f : 0.f) + (win1 ? 1.f : 0.f);
    if (c == 0)
        shG[g] = make_float4(s_obj, s_np, v_cls, v_box);
    __syncthreads();
    if (t == 0) {
        float4 r = make_float4(0.f, 0.f, 0.f, 0.f);
        #pragma unroll
        for (int k = 0; k < 8; ++k) {
            r.x += shG[k].x; r.y += shG[k].y; r.z += shG[k].z; r.w += shG[k].w;
        }
        Gout[gi] = r;
    }
}

__global__ void final_combine(const float* __restrict__ Aout, const float4* __restrict__ Gout,
                              float* __restrict__ out) {
    int t = threadIdx.x;
    // A sums per level
    float a0 = 0, a1 = 0, a2 = 0;
    for (int e = t; e < NA0; e += TPB)             a0 += Aout[e];
    for (int e = NA0 + t; e < NA0 + NA1; e += TPB) a1 += Aout[e];
    for (int e = NA0 + NA1 + t; e < NA; e += TPB)  a2 += Aout[e];
    // G sums per level (512 float4 each)
    float o0 = 0, n0 = 0, c0 = 0, b0 = 0;
    float o1 = 0, n1 = 0, c1 = 0, b1 = 0;
    float o2 = 0, n2 = 0, c2 = 0, b2 = 0;
    for (int e = t; e < NG_PER_LVL; e += TPB) {
        float4 v = Gout[e];                  o0 += v.x; n0 += v.y; c0 += v.z; b0 += v.w;
    }
    for (int e = t; e < NG_PER_LVL; e += TPB) {
        float4 v = Gout[NG_PER_LVL + e];     o1 += v.x; n1 += v.y; c1 += v.z; b1 += v.w;
    }
    for (int e = t; e < NG_PER_LVL; e += TPB) {
        float4 v = Gout[2 * NG_PER_LVL + e]; o2 += v.x; n2 += v.y; c2 += v.z; b2 += v.w;
    }
    a0 = wave_sum(a0); a1 = wave_sum(a1); a2 = wave_sum(a2);
    o0 = wave_sum(o0); n0 = wave_sum(n0); c0 = wave_sum(c0); b0 = wave_sum(b0);
    o1 = wave_sum(o1); n1 = wave_sum(n1); c1 = wave_sum(c1); b1 = wave_sum(b1);
    o2 = wave_sum(o2); n2 = wave_sum(n2); c2 = wave_sum(c2); b2 = wave_sum(b2);
    __shared__ float s[4][15];
    int wid = t >> 6, lane = t & 63;
    if (lane == 0) {
        s[wid][0] = a0; s[wid][1] = a1; s[wid][2] = a2;
        s[wid][3]  = o0; s[wid][4]  = n0; s[wid][5]  = c0; s[wid][6]  = b0;
        s[wid][7]  = o1; s[wid][8]  = n1; s[wid][9]  = c1; s[wid][10] = b1;
        s[wid][11] = o2; s[wid][12] = n2; s[wid][13] = c2; s[wid][14] = b2;
    }
    __syncthreads();
    if (t == 0) {
        float r[15];
        #pragma unroll
        for (int k = 0; k < 15; ++k)
            r[k] = s[0][k] + s[1][k] + s[2][k] + s[3][k];
        float np0 = fmaxf(r[4],  1.f);
        float np1 = fmaxf(r[8],  1.f);
        float np2 = fmaxf(r[12], 1.f);
        float lo = (r[0] + r[3])  / (float)C0
                 + (r[1] + r[7])  / (float)C1
                 + (r[2] + r[11]) / (float)C2;
        float lc = r[5] / np0 + r[9]  / np1 + r[13] / np2;
        float lb = r[6] / np0 + r[10] / np1 + r[14] / np2;
        out[0] = lc + lb + lo;
        out[1] = lc;
        out[2] = lb;
        out[3] = lo;
    }
}

extern "C" void kernel_launch(void* const* d_in, const int* in_sizes, int n_in,
                              void* d_out, int out_size, void* d_ws, size_t ws_size,
                              hipStream_t stream) {
    AllPtrs p;
    p.cls0 = (const float*)d_in[0]; p.box0 = (const float*)d_in[1]; p.obj0 = (const float*)d_in[2];
    p.cls1 = (const float*)d_in[3]; p.box1 = (const float*)d_in[4]; p.obj1 = (const float*)d_in[5];
    p.cls2 = (const float*)d_in[6]; p.box2 = (const float*)d_in[7]; p.obj2 = (const float*)d_in[8];
    const float4* boxes  = (const float4*)d_in[9];
    const int*    labels = (const int*)d_in[10];
    float* out = (float*)d_out;

    // workspace: Gout float4[1536] at 0 (24576 B), Aout float[2100] after
    char* ws = (char*)d_ws;
    float4* Gout = (float4*)ws;
    float*  Aout = (float*)(ws + NG * sizeof(float4));

    fused_loss<<<NBLK, TPB, 0, stream>>>(p, boxes, labels, Aout, Gout);
    final_combine<<<1, TPB, 0, stream>>>(Aout, Gout, out);
}

// Round 14
// 20.672 us; speedup vs baseline: 2.0079x; 1.1367x over previous
//
#include <hip/hip_runtime.h>

// YOLO-style multi-level detection loss — gridless, gather-parallel, 4-deep MLP.
// Input dict order (setup_inputs interleaves!):
//   d_in[0]=cls0 d_in[1]=box0 d_in[2]=obj0
//   d_in[3]=cls1 d_in[4]=box1 d_in[5]=obj1
//   d_in[6]=cls2 d_in[7]=box2 d_in[8]=obj2
//   d_in[9]=boxes [B,N,4]  d_in[10]=labels [B,N]
// Output: 4 floats: total, loss_cls, loss_box, loss_obj
//
// bce(x,t) = bce(x,0) - x*t for t in {0,1}:
//   loss_obj*cnt = sum_all bce0(obj) + sum_winners(-obj)
//   cls/box only need predictions AT positive cells.
// Ladder: 210us (latency, 1 wave/SIMD) -> 78 (occupancy) -> libm->v_exp/v_log
// -> 50 (gather from 32 blocks) -> 20 (1 thread/load) -> 17 (issue-early)
// -> 15 (2-deep). Now 4-deep: 4 entries per 32-lane group, 4 scattered loads
// in flight per thread before the shared shfl-OR scan; NG 1536->768.
// Winner/mask: batch's 64 cells in LDS; lane c probes boxes c and c+32 per
// entry; bit31 = "later box shares my cell" (last box wins = JAX sequential
// scatter-set); bits 0..19 = label mask. Lane c<20 = cls channel c, 20..23 =
// box channel, 24 = obj. No atomics, no ws clearing (poison-proof).

#define NCLS  20
#define BATCH 128
#define TPB   256
// cells per level (BATCH * H * W)
#define C0 819200
#define C1 204800
#define C2 51200
// G-blocks: 32 entries/block (8 groups x 4); 8192 entries/level -> 256/level
#define NG_PER_LVL 256
#define NG  (3 * NG_PER_LVL)    // 768
// A-blocks: stream bce0(obj); one float4 per thread (exact partitions)
#define NA0 800
#define NA1 200
#define NA2 50
#define NA  (NA0 + NA1 + NA2)   // 1050
#define NBLK (NG + NA)          // 1818

struct AllPtrs {
    const float *cls0, *box0, *obj0;
    const float *cls1, *box1, *obj1;
    const float *cls2, *box2, *obj2;
};

__device__ __forceinline__ float bce0(float x) {
    // bce_with_logits(x,0) = max(x,0) + log1p(exp(-|x|)); v_exp/v_log fast
    // form (log(1+e)==log1p(e) to fp32 for e in (2^-24,1]; abs err <=6e-8).
    return fmaxf(x, 0.0f) + __logf(1.0f + __expf(-fabsf(x)));
}

__device__ __forceinline__ float wave_sum(float v) {
    #pragma unroll
    for (int o = 32; o > 0; o >>= 1) v += __shfl_down(v, o);
    return v;
}

__global__ void __launch_bounds__(TPB)
fused_loss(AllPtrs p, const float4* __restrict__ boxes, const int* __restrict__ labels,
           float* __restrict__ Aout, float4* __restrict__ Gout) {
    __shared__ float  shA[4];
    __shared__ int    s_cell[64];
    __shared__ int    s_lab[64];
    __shared__ float  s_cx[64], s_cy[64], s_w[64], s_h[64];
    __shared__ float4 shG[8];

    int blk = blockIdx.x;
    if (blk >= NG) {
        // ---- A path: sum bce0(obj) over all cells of one level slice ----
        int a = blk - NG;
        const float* obj;
        int i;
        if (a < NA0)            { obj = p.obj0; i = a * TPB + threadIdx.x; }
        else if (a < NA0 + NA1) { obj = p.obj1; i = (a - NA0) * TPB + threadIdx.x; }
        else                    { obj = p.obj2; i = (a - NA0 - NA1) * TPB + threadIdx.x; }
        float4 v = ((const float4*)obj)[i];
        float s = bce0(v.x) + bce0(v.y) + bce0(v.z) + bce0(v.w);
        s = wave_sum(s);
        int wid = threadIdx.x >> 6, lane = threadIdx.x & 63;
        if (lane == 0) shA[wid] = s;
        __syncthreads();
        if (threadIdx.x == 0)
            Aout[a] = shA[0] + shA[1] + shA[2] + shA[3];
        return;
    }

    // ---- G path: one 32-lane group per FOUR (level,batch,box) entries ----
    int gi  = blk;                    // 0..767
    int l   = gi >> 8;                // level 0..2
    int rem = gi & (NG_PER_LVL - 1);  // 0..255
    int batch  = rem >> 1;            // 0..127 (2 blocks per batch)
    int base_n = (rem & 1) * 32;      // this block's 32 box indices

    const float is[3]  = {0.125f, 0.0625f, 0.03125f};
    const int   Ws[3]  = {80, 40, 20};
    const int   HWs[3] = {6400, 1600, 400};
    const float* clsP[3] = {p.cls0, p.cls1, p.cls2};
    const float* boxP[3] = {p.box0, p.box1, p.box2};
    const float* objP[3] = {p.obj0, p.obj1, p.obj2};
    const float isl = is[l];
    const int   Wl  = Ws[l];
    const int   HW  = HWs[l];

    int t = threadIdx.x;
    if (t < 64) {                    // stage batch geometry in LDS
        float4 bx = boxes[batch * 64 + t];
        float cx = (bx.x + bx.z) * 0.5f, cy = (bx.y + bx.w) * 0.5f;
        s_cx[t] = cx; s_cy[t] = cy;
        s_w[t]  = bx.z - bx.x; s_h[t] = bx.w - bx.y;
        s_lab[t] = labels[batch * 64 + t];
        int gx = (int)floorf(cx * isl);
        int gy = (int)floorf(cy * isl);
        bool valid = (gx >= 0) & (gy >= 0) & (gx < Wl) & (gy < Wl);
        s_cell[t] = valid ? gy * Wl + gx : -1;
    }
    __syncthreads();

    int g = t >> 5;                  // group 0..7
    int c = t & 31;                  // channel lane
    int n[4], cell[4], lc[4];
    #pragma unroll
    for (int e = 0; e < 4; ++e) {
        n[e]    = base_n + g + e * 8;
        cell[e] = s_cell[n[e]];
        lc[e]   = (cell[e] >= 0) ? cell[e] : 0;
    }

    // ---- ISSUE all 4 scattered loads EARLY (latency overlaps scan) ----
    float ld[4] = {0.f, 0.f, 0.f, 0.f};
    if (c < NCLS) {
        const float* cb = clsP[l] + (size_t)(batch * NCLS + c) * HW;
        #pragma unroll
        for (int e = 0; e < 4; ++e) ld[e] = cb[lc[e]];
    } else if (c < 24) {
        const float* bb = boxP[l] + (size_t)(batch * 4 + (c - 20)) * HW;
        #pragma unroll
        for (int e = 0; e < 4; ++e) ld[e] = bb[lc[e]];
    } else if (c == 24) {
        const float* ob = objP[l] + (size_t)batch * HW;
        #pragma unroll
        for (int e = 0; e < 4; ++e) ld[e] = ob[lc[e]];
    }

    // box-target values for lanes 20..23 (independent of loads)
    float tv[4] = {0.f, 0.f, 0.f, 0.f};
    if (c >= 20 && c < 24) {
        int k = c - 20;
        #pragma unroll
        for (int e = 0; e < 4; ++e) {
            if (k == 0)      { float sx = s_cx[n[e]] * isl; tv[e] = sx - floorf(sx); }
            else if (k == 1) { float sy = s_cy[n[e]] * isl; tv[e] = sy - floorf(sy); }
            else if (k == 2) { tv[e] = __logf(s_w[n[e]] * isl + 1e-6f); }
            else             { tv[e] = __logf(s_h[n[e]] * isl + 1e-6f); }
        }
    }

    // ---- winner + label-mask scan for all 4 entries (overlaps loads) ----
    int cj0 = s_cell[c], cj1 = s_cell[c + 32];
    unsigned lb0 = 1u << s_lab[c], lb1 = 1u << s_lab[c + 32];
    unsigned comb[4];
    #pragma unroll
    for (int e = 0; e < 4; ++e) {
        unsigned cm = 0u;            // bits0..19 mask, bit31 violation
        if (cell[e] >= 0) {
            if (cj0 == cell[e]) cm |= lb0 | ((c > n[e])      ? 0x80000000u : 0u);
            if (cj1 == cell[e]) cm |= lb1 | ((c + 32 > n[e]) ? 0x80000000u : 0u);
        }
        comb[e] = cm;
    }
    #pragma unroll
    for (int o = 16; o > 0; o >>= 1) {
        #pragma unroll
        for (int e = 0; e < 4; ++e)
            comb[e] |= (unsigned)__shfl_xor((int)comb[e], o, 32);
    }

    // ---- apply win/mask to loaded values ----
    float v_cls = 0.f, v_box = 0.f, v_obj = 0.f, v_np = 0.f;
    #pragma unroll
    for (int e = 0; e < 4; ++e) {
        bool win = (cell[e] >= 0) && !(comb[e] >> 31);
        unsigned mask = comb[e] & 0xFFFFFu;
        if (win) {
            v_np += 0.25f;           // 4 entries -> np counted once per lane-set; scaled below
            if (c < NCLS) {
                v_cls += bce0(ld[e]) - (((mask >> c) & 1u) ? ld[e] : 0.f);
            } else if (c < 24) {
                float d = fabsf(ld[e] - tv[e]);
                v_box += (d < 1.f) ? 0.5f * d * d : d - 0.5f;
            } else if (c == 24) {
                v_obj -= ld[e];      // bce(x,1)=bce0(x)-x
            }
        }
    }
    // np: every active lane of the group added 0.25 per win -> after the
    // 32-lane sum this would be 8x too big; instead count wins only on lane 0.
    v_np = (c == 0) ? v_np * 4.f : 0.f;   // lane0: 0.25*4=1 per win

    #pragma unroll
    for (int o = 16; o > 0; o >>= 1) {
        v_cls += __shfl_down(v_cls, o, 32);
        v_box += __shfl_down(v_box, o, 32);
    }
    float s_obj = __shfl(v_obj, 24, 32);
    if (c == 0)
        shG[g] = make_float4(s_obj, v_np, v_cls, v_box);
    __syncthreads();
    if (t == 0) {
        float4 r = make_float4(0.f, 0.f, 0.f, 0.f);
        #pragma unroll
        for (int k = 0; k < 8; ++k) {
            r.x += shG[k].x; r.y += shG[k].y; r.z += shG[k].z; r.w += shG[k].w;
        }
        Gout[gi] = r;
    }
}

__global__ void final_combine(const float* __restrict__ Aout, const float4* __restrict__ Gout,
                              float* __restrict__ out) {
    int t = threadIdx.x;
    // A sums per level
    float a0 = 0, a1 = 0, a2 = 0;
    for (int e = t; e < NA0; e += TPB)             a0 += Aout[e];
    for (int e = NA0 + t; e < NA0 + NA1; e += TPB) a1 += Aout[e];
    for (int e = NA0 + NA1 + t; e < NA; e += TPB)  a2 += Aout[e];
    // G sums per level (256 float4 each)
    float o0 = 0, n0 = 0, c0 = 0, b0 = 0;
    float o1 = 0, n1 = 0, c1 = 0, b1 = 0;
    float o2 = 0, n2 = 0, c2 = 0, b2 = 0;
    for (int e = t; e < NG_PER_LVL; e += TPB) {
        float4 v = Gout[e];                  o0 += v.x; n0 += v.y; c0 += v.z; b0 += v.w;
    }
    for (int e = t; e < NG_PER_LVL; e += TPB) {
        float4 v = Gout[NG_PER_LVL + e];     o1 += v.x; n1 += v.y; c1 += v.z; b1 += v.w;
    }
    for (int e = t; e < NG_PER_LVL; e += TPB) {
        float4 v = Gout[2 * NG_PER_LVL + e]; o2 += v.x; n2 += v.y; c2 += v.z; b2 += v.w;
    }
    a0 = wave_sum(a0); a1 = wave_sum(a1); a2 = wave_sum(a2);
    o0 = wave_sum(o0); n0 = wave_sum(n0); c0 = wave_sum(c0); b0 = wave_sum(b0);
    o1 = wave_sum(o1); n1 = wave_sum(n1); c1 = wave_sum(c1); b1 = wave_sum(b1);
    o2 = wave_sum(o2); n2 = wave_sum(n2); c2 = wave_sum(c2); b2 = wave_sum(b2);
    __shared__ float s[4][15];
    int wid = t >> 6, lane = t & 63;
    if (lane == 0) {
        s[wid][0] = a0; s[wid][1] = a1; s[wid][2] = a2;
        s[wid][3]  = o0; s[wid][4]  = n0; s[wid][5]  = c0; s[wid][6]  = b0;
        s[wid][7]  = o1; s[wid][8]  = n1; s[wid][9]  = c1; s[wid][10] = b1;
        s[wid][11] = o2; s[wid][12] = n2; s[wid][13] = c2; s[wid][14] = b2;
    }
    __syncthreads();
    if (t == 0) {
        float r[15];
        #pragma unroll
        for (int k = 0; k < 15; ++k)
            r[k] = s[0][k] + s[1][k] + s[2][k] + s[3][k];
        float np0 = fmaxf(r[4],  1.f);
        float np1 = fmaxf(r[8],  1.f);
        float np2 = fmaxf(r[12], 1.f);
        float lo = (r[0] + r[3])  / (float)C0
                 + (r[1] + r[7])  / (float)C1
                 + (r[2] + r[11]) / (float)C2;
        float lc = r[5] / np0 + r[9]  / np1 + r[13] / np2;
        float lb = r[6] / np0 + r[10] / np1 + r[14] / np2;
        out[0] = lc + lb + lo;
        out[1] = lc;
        out[2] = lb;
        out[3] = lo;
    }
}

extern "C" void kernel_launch(void* const* d_in, const int* in_sizes, int n_in,
                              void* d_out, int out_size, void* d_ws, size_t ws_size,
                              hipStream_t stream) {
    AllPtrs p;
    p.cls0 = (const float*)d_in[0]; p.box0 = (const float*)d_in[1]; p.obj0 = (const float*)d_in[2];
    p.cls1 = (const float*)d_in[3]; p.box1 = (const float*)d_in[4]; p.obj1 = (const float*)d_in[5];
    p.cls2 = (const float*)d_in[6]; p.box2 = (const float*)d_in[7]; p.obj2 = (const float*)d_in[8];
    const float4* boxes  = (const float4*)d_in[9];
    const int*    labels = (const int*)d_in[10];
    float* out = (float*)d_out;

    // workspace: Gout float4[768] at 0 (12288 B), Aout float[1050] after
    char* ws = (char*)d_ws;
    float4* Gout = (float4*)ws;
    float*  Aout = (float*)(ws + NG * sizeof(float4));

    fused_loss<<<NBLK, TPB, 0, stream>>>(p, boxes, labels, Aout, Gout);
    final_combine<<<1, TPB, 0, stream>>>(Aout, Gout, out);
}